// Round 2
// baseline (3038.584 us; speedup 1.0000x reference)
//
#include <hip/hip_runtime.h>
#include <hip/hip_bf16.h>

// ---------------------------------------------------------------------------
// HeteroIncidentGATv2: 3 bipartite GATv2 relations (H=4, C=32, HC=128)
//   hs: host->switch (200K edges), vh: vm->host (400K), jv: job->vm (800K)
//
// R2 changes vs R1 (which core-dumped, likely d_ws overflow at 365 MB):
//   - relations processed SEQUENTIALLY through one arena (peak 157 MB)
//   - xr buffer reused as the output accumulator (xr dead after logits)
//   - logits/ex/alpha stored in d_out's alpha region (it's ours to scribble)
//   - hipMemsetAsync replaced by a zero-fill kernel (graph-capture safety)
// ---------------------------------------------------------------------------

#define SLOPE_ATT 0.2f
#define SLOPE_OUT 0.01f

__device__ inline unsigned fenc(float f) {
    unsigned u = __float_as_uint(f);
    return u ^ ((u >> 31) ? 0xFFFFFFFFu : 0x80000000u);
}
__device__ inline float fdec(unsigned k) {
    unsigned u = k ^ ((k >> 31) ? 0x80000000u : 0xFFFFFFFFu);
    return __uint_as_float(u);
}

__device__ inline void atomAddF(float* p, float v) {
    // HW global_atomic_add_f32 (plain atomicAdd may emit a CAS loop without
    // -munsafe-fp-atomics). gfx90a+.
    unsafeAtomicAdd(p, v);
}

// ---------------------------------------------------------------------------
__global__ __launch_bounds__(256) void zero_kernel(float4* __restrict__ p, size_t n4) {
    size_t i = (size_t)blockIdx.x * 256 + threadIdx.x;
    size_t stride = (size_t)gridDim.x * 256;
    float4 z = make_float4(0.f, 0.f, 0.f, 0.f);
    for (; i < n4; i += stride) p[i] = z;
}

// ---------------------------------------------------------------------------
// GEMM: Y[M,128] = X[M,64] @ W[64,128] + b[128]
// 64-row tile per 256-thread block; W fully resident in LDS (32 KB).
// ---------------------------------------------------------------------------
__global__ __launch_bounds__(256) void gemm_xw_kernel(
    const float* __restrict__ X, const float* __restrict__ W,
    const float* __restrict__ b, float* __restrict__ Y, int M) {
    __shared__ float sW[64 * 128];      // [k][n] row-major, 32 KB
    __shared__ float sX[64][68];        // 64 rows x 64 cols, pad to 68

    const int tid = threadIdx.x;
    const int block_row = blockIdx.x * 64;

    for (int i = tid; i < 64 * 128 / 4; i += 256)
        ((float4*)sW)[i] = ((const float4*)W)[i];

    for (int i = tid; i < 64 * 16; i += 256) {
        int r = i >> 4, c4 = i & 15;
        int gr = block_row + r;
        float4 v = make_float4(0.f, 0.f, 0.f, 0.f);
        if (gr < M) v = ((const float4*)X)[(size_t)gr * 16 + c4];
        *(float4*)&sX[r][c4 * 4] = v;
    }
    __syncthreads();

    const int tx = tid & 31;   // col group (4 cols each)
    const int ty = tid >> 5;   // row base

    float acc[8][4] = {};
    for (int k = 0; k < 64; k += 4) {
        float4 w0 = *(const float4*)&sW[(k + 0) * 128 + tx * 4];
        float4 w1 = *(const float4*)&sW[(k + 1) * 128 + tx * 4];
        float4 w2 = *(const float4*)&sW[(k + 2) * 128 + tx * 4];
        float4 w3 = *(const float4*)&sW[(k + 3) * 128 + tx * 4];
#pragma unroll
        for (int r = 0; r < 8; r++) {
            float4 xv = *(const float4*)&sX[ty + r * 8][k];
            acc[r][0] += xv.x * w0.x + xv.y * w1.x + xv.z * w2.x + xv.w * w3.x;
            acc[r][1] += xv.x * w0.y + xv.y * w1.y + xv.z * w2.y + xv.w * w3.y;
            acc[r][2] += xv.x * w0.z + xv.y * w1.z + xv.z * w2.z + xv.w * w3.z;
            acc[r][3] += xv.x * w0.w + xv.y * w1.w + xv.z * w2.w + xv.w * w3.w;
        }
    }

    float4 bv = ((const float4*)b)[tx];
#pragma unroll
    for (int r = 0; r < 8; r++) {
        int gr = block_row + ty + r * 8;
        if (gr < M) {
            float4 o = make_float4(acc[r][0] + bv.x, acc[r][1] + bv.y,
                                   acc[r][2] + bv.z, acc[r][3] + bv.w);
            ((float4*)Y)[(size_t)gr * 32 + tx] = o;
        }
    }
}

// ---------------------------------------------------------------------------
// Edge logits: 16 lanes per edge, each lane 8 channels (2 float4).
// logit[e,h] = sum_c lrelu(xl[src][h,c] + xr[dst][h,c], 0.2) * att[h,c]
// Also atomicMax into per-(dst,head) ordered-uint max (0 == -inf sentinel:
// fenc of any finite float is > 0).
// ---------------------------------------------------------------------------
__global__ __launch_bounds__(256) void edge_logits_kernel(
    const float* __restrict__ xl, const float* __restrict__ xr,
    const int* __restrict__ src, const int* __restrict__ dst,
    const float* __restrict__ att, float* __restrict__ logits,
    unsigned* __restrict__ mkey, int E) {
    int t = blockIdx.x * 256 + threadIdx.x;
    int e = t >> 4;
    int l = t & 15;
    if (e >= E) return;
    int s = src[e], d = dst[e];
    const float4* pl = (const float4*)(xl + (size_t)s * 128) + l * 2;
    const float4* pr = (const float4*)(xr + (size_t)d * 128) + l * 2;
    const float4* pa = (const float4*)att + l * 2;
    float acc = 0.f;
#pragma unroll
    for (int j = 0; j < 2; j++) {
        float4 a = pl[j], b = pr[j], w = pa[j];
        float v;
        v = a.x + b.x; v = v > 0.f ? v : SLOPE_ATT * v; acc += v * w.x;
        v = a.y + b.y; v = v > 0.f ? v : SLOPE_ATT * v; acc += v * w.y;
        v = a.z + b.z; v = v > 0.f ? v : SLOPE_ATT * v; acc += v * w.z;
        v = a.w + b.w; v = v > 0.f ? v : SLOPE_ATT * v; acc += v * w.w;
    }
    // reduce the 4 lanes covering one head (lanes l, l^1, l^2 share l>>2)
    acc += __shfl_xor(acc, 1);
    acc += __shfl_xor(acc, 2);
    if ((l & 3) == 0) {
        int h = l >> 2;
        logits[(size_t)e * 4 + h] = acc;
        atomicMax(&mkey[(size_t)d * 4 + h], fenc(acc));
    }
}

// ---------------------------------------------------------------------------
// ex = exp(logit - m[dst]); denom[dst,h] += ex   (logits updated in place)
// ---------------------------------------------------------------------------
__global__ __launch_bounds__(256) void edge_exp_kernel(
    float* __restrict__ logits, const unsigned* __restrict__ mkey,
    const int* __restrict__ dst, float* __restrict__ denom, int E4) {
    int i = blockIdx.x * 256 + threadIdx.x;
    if (i >= E4) return;
    int e = i >> 2, h = i & 3;
    int d = dst[e];
    float m = fdec(mkey[d * 4 + h]);
    float v = __expf(logits[i] - m);
    logits[i] = v;
    atomAddF(&denom[d * 4 + h], v);
}

// ---------------------------------------------------------------------------
// alpha = ex/denom -> written back in place; outacc[dst] += alpha * xl[src]
// 32 lanes per edge (1 float4 of channels each). One edge never spans a wave
// (32 | 64), so the in-place alpha store is ordered after all its reads.
// ---------------------------------------------------------------------------
__global__ __launch_bounds__(256) void edge_scatter_kernel(
    float* __restrict__ ex_alpha, const float* __restrict__ denom,
    const int* __restrict__ src, const int* __restrict__ dst,
    const float* __restrict__ xl, float* __restrict__ outacc, int E) {
    int t = blockIdx.x * 256 + threadIdx.x;
    int e = t >> 5;
    int l = t & 31;
    if (e >= E) return;
    int s = src[e], d = dst[e];
    int h = l >> 3;
    float a = ex_alpha[(size_t)e * 4 + h] / denom[(size_t)d * 4 + h];
    if ((l & 7) == 0) ex_alpha[(size_t)e * 4 + h] = a;
    float4 x = ((const float4*)(xl + (size_t)s * 128))[l];
    float* o = outacc + (size_t)d * 128 + l * 4;
    atomAddF(o + 0, x.x * a);
    atomAddF(o + 1, x.y * a);
    atomAddF(o + 2, x.z * a);
    atomAddF(o + 3, x.w * a);
}

// ---------------------------------------------------------------------------
// Readout: scores[n] = sigmoid(lrelu(out[n]+bias, 0.01) . Wn + bn)
// 32 lanes per node.
// ---------------------------------------------------------------------------
__global__ __launch_bounds__(256) void readout_kernel(
    const float* __restrict__ outacc, const float* __restrict__ bias,
    const float* __restrict__ Wn, const float* __restrict__ bn,
    float* __restrict__ scores, int N) {
    int t = blockIdx.x * 256 + threadIdx.x;
    int node = t >> 5;
    int l = t & 31;
    if (node >= N) return;
    float4 v = ((const float4*)(outacc + (size_t)node * 128))[l];
    float4 bb = ((const float4*)bias)[l];
    float4 w = ((const float4*)Wn)[l];
    float a0 = v.x + bb.x; a0 = a0 > 0.f ? a0 : SLOPE_OUT * a0;
    float a1 = v.y + bb.y; a1 = a1 > 0.f ? a1 : SLOPE_OUT * a1;
    float a2 = v.z + bb.z; a2 = a2 > 0.f ? a2 : SLOPE_OUT * a2;
    float a3 = v.w + bb.w; a3 = a3 > 0.f ? a3 : SLOPE_OUT * a3;
    float acc = a0 * w.x + a1 * w.y + a2 * w.z + a3 * w.w;
#pragma unroll
    for (int off = 1; off < 32; off <<= 1) acc += __shfl_xor(acc, off);
    if (l == 0) {
        float z = acc + bn[0];
        scores[node] = 1.f / (1.f + __expf(-z));
    }
}

__global__ __launch_bounds__(256) void job_fill_kernel(
    const float* __restrict__ bn, float* __restrict__ scores, int N) {
    int i = blockIdx.x * 256 + threadIdx.x;
    if (i < N) scores[i] = 1.f / (1.f + __expf(-bn[0]));
}

// ---------------------------------------------------------------------------

extern "C" void kernel_launch(void* const* d_in, const int* in_sizes, int n_in,
                              void* d_out, int out_size, void* d_ws, size_t ws_size,
                              hipStream_t stream) {
    const float* x_host   = (const float*)d_in[0];
    const float* x_vm     = (const float*)d_in[1];
    const float* x_job    = (const float*)d_in[2];
    const float* x_switch = (const float*)d_in[3];
    const int* e_hs_src = (const int*)d_in[4];
    const int* e_hs_dst = (const int*)d_in[5];
    const int* e_vh_src = (const int*)d_in[6];
    const int* e_vh_dst = (const int*)d_in[7];
    const int* e_jv_src = (const int*)d_in[8];
    const int* e_jv_dst = (const int*)d_in[9];
    const float* Wl_hs = (const float*)d_in[10];
    const float* bl_hs = (const float*)d_in[11];
    const float* Wr_hs = (const float*)d_in[12];
    const float* br_hs = (const float*)d_in[13];
    const float* att_hs = (const float*)d_in[14];
    const float* bias_hs = (const float*)d_in[15];
    const float* Wl_vh = (const float*)d_in[16];
    const float* bl_vh = (const float*)d_in[17];
    const float* Wr_vh = (const float*)d_in[18];
    const float* br_vh = (const float*)d_in[19];
    const float* att_vh = (const float*)d_in[20];
    const float* bias_vh = (const float*)d_in[21];
    const float* Wl_jv = (const float*)d_in[22];
    const float* bl_jv = (const float*)d_in[23];
    const float* Wr_jv = (const float*)d_in[24];
    const float* br_jv = (const float*)d_in[25];
    const float* att_jv = (const float*)d_in[26];
    const float* bias_jv = (const float*)d_in[27];
    const float* W_host   = (const float*)d_in[28];
    const float* b_host   = (const float*)d_in[29];
    const float* W_vm     = (const float*)d_in[30];
    const float* b_vm     = (const float*)d_in[31];
    const float* W_job    = (const float*)d_in[32];
    const float* b_job    = (const float*)d_in[33];
    const float* W_switch = (const float*)d_in[34];
    const float* b_switch = (const float*)d_in[35];

    const int NH  = in_sizes[0] / 64;   // 50000 hosts
    const int NV  = in_sizes[1] / 64;   // 100000 vms
    const int NJ  = in_sizes[2] / 64;   // 200000 jobs
    const int NSW = in_sizes[3] / 64;   // 5000 switches
    const int EHS = in_sizes[4];        // 200000
    const int EVH = in_sizes[6];        // 400000
    const int EJV = in_sizes[8];        // 800000

    // output layout: scores (NH,NV,NJ,NSW) then a_hs, a_vh, a_jv [E,4]
    float* out = (float*)d_out;
    float* s_host = out;
    float* s_vm = out + NH;
    float* s_job = out + NH + NV;
    float* s_sw = out + NH + NV + NJ;
    float* a_hs = out + NH + NV + NJ + NSW;
    float* a_vh = a_hs + (size_t)EHS * 4;
    float* a_jv = a_vh + (size_t)EVH * 4;

    float* ws = (float*)d_ws;

    // One relation end-to-end, arena-reused across relations.
    // Arena layout: xl [Ns*128] | buf [Nd*128] (xr, then reused as outacc)
    //             | mk [Nd*4] (u32) | dn [Nd*4]
    auto run_rel = [&](const float* x_src, int Ns, const float* x_dst, int Nd,
                       const int* esrc, const int* edst, int E,
                       const float* Wl, const float* bl,
                       const float* Wr, const float* br,
                       const float* att, const float* bias,
                       const float* Wn, const float* bn,
                       float* alpha, float* scores) {
        float* xl = ws;
        float* buf = xl + (size_t)Ns * 128;          // xr, later outacc
        unsigned* mk = (unsigned*)(buf + (size_t)Nd * 128);
        float* dn = (float*)(mk + (size_t)Nd * 4);

        gemm_xw_kernel<<<(Ns + 63) / 64, 256, 0, stream>>>(x_src, Wl, bl, xl, Ns);
        gemm_xw_kernel<<<(Nd + 63) / 64, 256, 0, stream>>>(x_dst, Wr, br, buf, Nd);

        // zero mk+dn (contiguous, Nd*8 floats)
        {
            size_t n4 = (size_t)Nd * 2;
            int blocks = (int)((n4 + 255) / 256);
            if (blocks > 4096) blocks = 4096;
            zero_kernel<<<blocks, 256, 0, stream>>>((float4*)mk, n4);
        }

        edge_logits_kernel<<<((size_t)E * 16 + 255) / 256, 256, 0, stream>>>(
            xl, buf, esrc, edst, att, alpha, mk, E);
        edge_exp_kernel<<<((size_t)E * 4 + 255) / 256, 256, 0, stream>>>(
            alpha, mk, edst, dn, E * 4);

        // buf (xr) is dead now -> becomes outacc; zero it
        {
            size_t n4 = (size_t)Nd * 32;
            int blocks = (int)((n4 + 255) / 256);
            if (blocks > 8192) blocks = 8192;
            zero_kernel<<<blocks, 256, 0, stream>>>((float4*)buf, n4);
        }

        edge_scatter_kernel<<<((size_t)E * 32 + 255) / 256, 256, 0, stream>>>(
            alpha, dn, esrc, edst, xl, buf, E);

        readout_kernel<<<((size_t)Nd * 32 + 255) / 256, 256, 0, stream>>>(
            buf, bias, Wn, bn, scores, Nd);
    };

    // hs: host -> switch
    run_rel(x_host, NH, x_switch, NSW, e_hs_src, e_hs_dst, EHS,
            Wl_hs, bl_hs, Wr_hs, br_hs, att_hs, bias_hs,
            W_switch, b_switch, a_hs, s_sw);
    // vh: vm -> host
    run_rel(x_vm, NV, x_host, NH, e_vh_src, e_vh_dst, EVH,
            Wl_vh, bl_vh, Wr_vh, br_vh, att_vh, bias_vh,
            W_host, b_host, a_vh, s_host);
    // jv: job -> vm
    run_rel(x_job, NJ, x_vm, NV, e_jv_src, e_jv_dst, EJV,
            Wl_jv, bl_jv, Wr_jv, br_jv, att_jv, bias_jv,
            W_vm, b_vm, a_jv, s_vm);

    // jobs have no incoming edges: score = sigmoid(b_job)
    job_fill_kernel<<<(NJ + 255) / 256, 256, 0, stream>>>(b_job, s_job, NJ);
}

// Round 3
// 1131.566 us; speedup vs baseline: 2.6853x; 2.6853x over previous
//
#include <hip/hip_runtime.h>
#include <hip/hip_bf16.h>

// ---------------------------------------------------------------------------
// HeteroIncidentGATv2: 3 bipartite GATv2 relations (H=4, C=32, HC=128)
//   hs: host->switch (200K edges), vh: vm->host (400K), jv: job->vm (800K)
//
// R3 changes vs R2 (3039 us, edge_scatter = 2.3 ms of it, atomic-bound,
// VALUBusy 2%):
//   - CSR build per relation (hist -> scan -> fill), then one 64-lane wave
//     per dst node gathers+reduces its edges in registers. ZERO fp atomics
//     in the aggregation path.
//   - readout fused into the aggregate epilogue; outacc buffer and its
//     zero-fill kernel removed.
// ---------------------------------------------------------------------------

#define SLOPE_ATT 0.2f
#define SLOPE_OUT 0.01f

__device__ inline unsigned fenc(float f) {
    unsigned u = __float_as_uint(f);
    return u ^ ((u >> 31) ? 0xFFFFFFFFu : 0x80000000u);
}
__device__ inline float fdec(unsigned k) {
    unsigned u = k ^ ((k >> 31) ? 0x80000000u : 0xFFFFFFFFu);
    return __uint_as_float(u);
}

__device__ inline void atomAddF(float* p, float v) {
    unsafeAtomicAdd(p, v);   // HW global_atomic_add_f32
}

// ---------------------------------------------------------------------------
__global__ __launch_bounds__(256) void zero_words_kernel(int* __restrict__ p, size_t n) {
    size_t i = (size_t)blockIdx.x * 256 + threadIdx.x;
    size_t stride = (size_t)gridDim.x * 256;
    for (; i < n; i += stride) p[i] = 0;
}

// ---------------------------------------------------------------------------
// GEMM: Y[M,128] = X[M,64] @ W[64,128] + b[128]
// ---------------------------------------------------------------------------
__global__ __launch_bounds__(256) void gemm_xw_kernel(
    const float* __restrict__ X, const float* __restrict__ W,
    const float* __restrict__ b, float* __restrict__ Y, int M) {
    __shared__ float sW[64 * 128];
    __shared__ float sX[64][68];

    const int tid = threadIdx.x;
    const int block_row = blockIdx.x * 64;

    for (int i = tid; i < 64 * 128 / 4; i += 256)
        ((float4*)sW)[i] = ((const float4*)W)[i];

    for (int i = tid; i < 64 * 16; i += 256) {
        int r = i >> 4, c4 = i & 15;
        int gr = block_row + r;
        float4 v = make_float4(0.f, 0.f, 0.f, 0.f);
        if (gr < M) v = ((const float4*)X)[(size_t)gr * 16 + c4];
        *(float4*)&sX[r][c4 * 4] = v;
    }
    __syncthreads();

    const int tx = tid & 31;
    const int ty = tid >> 5;

    float acc[8][4] = {};
    for (int k = 0; k < 64; k += 4) {
        float4 w0 = *(const float4*)&sW[(k + 0) * 128 + tx * 4];
        float4 w1 = *(const float4*)&sW[(k + 1) * 128 + tx * 4];
        float4 w2 = *(const float4*)&sW[(k + 2) * 128 + tx * 4];
        float4 w3 = *(const float4*)&sW[(k + 3) * 128 + tx * 4];
#pragma unroll
        for (int r = 0; r < 8; r++) {
            float4 xv = *(const float4*)&sX[ty + r * 8][k];
            acc[r][0] += xv.x * w0.x + xv.y * w1.x + xv.z * w2.x + xv.w * w3.x;
            acc[r][1] += xv.x * w0.y + xv.y * w1.y + xv.z * w2.y + xv.w * w3.y;
            acc[r][2] += xv.x * w0.z + xv.y * w1.z + xv.z * w2.z + xv.w * w3.z;
            acc[r][3] += xv.x * w0.w + xv.y * w1.w + xv.z * w2.w + xv.w * w3.w;
        }
    }

    float4 bv = ((const float4*)b)[tx];
#pragma unroll
    for (int r = 0; r < 8; r++) {
        int gr = block_row + ty + r * 8;
        if (gr < M) {
            float4 o = make_float4(acc[r][0] + bv.x, acc[r][1] + bv.y,
                                   acc[r][2] + bv.z, acc[r][3] + bv.w);
            ((float4*)Y)[(size_t)gr * 32 + tx] = o;
        }
    }
}

// ---------------------------------------------------------------------------
// CSR build: histogram -> 3-kernel exclusive scan -> fill
// ---------------------------------------------------------------------------
__global__ __launch_bounds__(256) void hist_kernel(
    const int* __restrict__ dst, int* __restrict__ hist, int E) {
    int i = blockIdx.x * 256 + threadIdx.x;
    int stride = gridDim.x * 256;
    for (; i < E; i += stride) atomicAdd(&hist[dst[i]], 1);
}

// per-256 block scan: rowptr[i] = exclusive-within-block, bsum[b] = block total
__global__ __launch_bounds__(256) void scan1_kernel(
    const int* __restrict__ hist, int* __restrict__ rowptr,
    int* __restrict__ bsum, int n) {
    __shared__ int s[256];
    int tid = threadIdx.x;
    int i = blockIdx.x * 256 + tid;
    int v = (i < n) ? hist[i] : 0;
    s[tid] = v;
    __syncthreads();
    for (int off = 1; off < 256; off <<= 1) {
        int t = (tid >= off) ? s[tid - off] : 0;
        __syncthreads();
        s[tid] += t;
        __syncthreads();
    }
    if (i < n) rowptr[i] = s[tid] - v;
    if (tid == 255) bsum[blockIdx.x] = s[255];
}

// single-block exclusive scan of block sums (nb <= 512 here: Nd <= 100000)
__global__ __launch_bounds__(512) void scan2_kernel(int* __restrict__ bsum, int nb) {
    __shared__ int s[512];
    int tid = threadIdx.x;
    int v = (tid < nb) ? bsum[tid] : 0;
    s[tid] = v;
    __syncthreads();
    for (int off = 1; off < 512; off <<= 1) {
        int t = (tid >= off) ? s[tid - off] : 0;
        __syncthreads();
        s[tid] += t;
        __syncthreads();
    }
    if (tid < nb) bsum[tid] = s[tid] - v;
}

// add block offsets; also mirror into fillpos; write rowptr[n] = E
__global__ __launch_bounds__(256) void scan3_kernel(
    int* __restrict__ rowptr, int* __restrict__ fillpos,
    const int* __restrict__ bsum, int n, int E) {
    int i = blockIdx.x * 256 + threadIdx.x;
    if (i < n) {
        int v = rowptr[i] + bsum[blockIdx.x];
        rowptr[i] = v;
        fillpos[i] = v;
    }
    if (i == 0) rowptr[n] = E;
}

__global__ __launch_bounds__(256) void fill_kernel(
    const int* __restrict__ dst, int* __restrict__ fillpos,
    int* __restrict__ eidx, int E) {
    int i = blockIdx.x * 256 + threadIdx.x;
    int stride = gridDim.x * 256;
    for (; i < E; i += stride) {
        int pos = atomicAdd(&fillpos[dst[i]], 1);
        eidx[pos] = i;
    }
}

// ---------------------------------------------------------------------------
// Edge logits: 16 lanes per edge, each lane 8 channels (2 float4).
// logit[e,h] = sum_c lrelu(xl[src][h,c] + xr[dst][h,c], 0.2) * att[h,c]
// atomicMax into per-(dst,head) ordered-uint max (0-init == -inf sentinel).
// ---------------------------------------------------------------------------
__global__ __launch_bounds__(256) void edge_logits_kernel(
    const float* __restrict__ xl, const float* __restrict__ xr,
    const int* __restrict__ src, const int* __restrict__ dst,
    const float* __restrict__ att, float* __restrict__ logits,
    unsigned* __restrict__ mkey, int E) {
    int t = blockIdx.x * 256 + threadIdx.x;
    int e = t >> 4;
    int l = t & 15;
    if (e >= E) return;
    int s = src[e], d = dst[e];
    const float4* pl = (const float4*)(xl + (size_t)s * 128) + l * 2;
    const float4* pr = (const float4*)(xr + (size_t)d * 128) + l * 2;
    const float4* pa = (const float4*)att + l * 2;
    float acc = 0.f;
#pragma unroll
    for (int j = 0; j < 2; j++) {
        float4 a = pl[j], b = pr[j], w = pa[j];
        float v;
        v = a.x + b.x; v = v > 0.f ? v : SLOPE_ATT * v; acc += v * w.x;
        v = a.y + b.y; v = v > 0.f ? v : SLOPE_ATT * v; acc += v * w.y;
        v = a.z + b.z; v = v > 0.f ? v : SLOPE_ATT * v; acc += v * w.z;
        v = a.w + b.w; v = v > 0.f ? v : SLOPE_ATT * v; acc += v * w.w;
    }
    acc += __shfl_xor(acc, 1);
    acc += __shfl_xor(acc, 2);
    if ((l & 3) == 0) {
        int h = l >> 2;
        logits[(size_t)e * 4 + h] = acc;
        atomicMax(&mkey[(size_t)d * 4 + h], fenc(acc));
    }
}

// ---------------------------------------------------------------------------
// ex = exp(logit - m[dst]); denom[dst,h] += ex   (logits -> ex in place)
// ---------------------------------------------------------------------------
__global__ __launch_bounds__(256) void edge_exp_kernel(
    float* __restrict__ logits, const unsigned* __restrict__ mkey,
    const int* __restrict__ dst, float* __restrict__ denom, int E4) {
    int i = blockIdx.x * 256 + threadIdx.x;
    if (i >= E4) return;
    int e = i >> 2, h = i & 3;
    int d = dst[e];
    float m = fdec(mkey[d * 4 + h]);
    float v = __expf(logits[i] - m);
    logits[i] = v;
    atomAddF(&denom[d * 4 + h], v);
}

// ---------------------------------------------------------------------------
// Aggregate + readout, one 64-lane wave per dst node (2 channels/lane).
//   alpha = ex/denom -> written to alpha region (in place over ex)
//   acc += alpha * xl[src]  (registers; NO atomics)
//   scores[d] = sigmoid(lrelu(acc + bias, 0.01) . Wn + bn)
// ---------------------------------------------------------------------------
__global__ __launch_bounds__(256) void aggregate_kernel(
    float* __restrict__ ex_alpha, const float* __restrict__ denom,
    const int* __restrict__ rowptr, const int* __restrict__ eidx,
    const int* __restrict__ src, const float* __restrict__ xl,
    const float* __restrict__ bias, const float* __restrict__ Wn,
    const float* __restrict__ bn, float* __restrict__ scores, int Nd) {
    int wid = (blockIdx.x * 256 + threadIdx.x) >> 6;   // dst node
    int l = threadIdx.x & 63;                          // lane: channels 2l,2l+1
    if (wid >= Nd) return;
    int d = wid;
    int h = l >> 4;                                    // head of my channels
    int beg = rowptr[d], end = rowptr[d + 1];
    float dnh = denom[(size_t)d * 4 + h];              // valid iff end > beg

    float2 acc = make_float2(0.f, 0.f);
    for (int j = beg; j < end; j++) {
        int e = eidx[j];
        int s = src[e];
        float a = ex_alpha[(size_t)e * 4 + h] / dnh;
        if ((l & 15) == 0) ex_alpha[(size_t)e * 4 + h] = a;
        float2 x = ((const float2*)(xl + (size_t)s * 128))[l];
        acc.x += a * x.x;
        acc.y += a * x.y;
    }

    float2 bb = ((const float2*)bias)[l];
    float2 w = ((const float2*)Wn)[l];
    float o0 = acc.x + bb.x; o0 = o0 > 0.f ? o0 : SLOPE_OUT * o0;
    float o1 = acc.y + bb.y; o1 = o1 > 0.f ? o1 : SLOPE_OUT * o1;
    float p = o0 * w.x + o1 * w.y;
#pragma unroll
    for (int off = 1; off < 64; off <<= 1) p += __shfl_xor(p, off);
    if (l == 0) scores[d] = 1.f / (1.f + __expf(-(p + bn[0])));
}

__global__ __launch_bounds__(256) void job_fill_kernel(
    const float* __restrict__ bn, float* __restrict__ scores, int N) {
    int i = blockIdx.x * 256 + threadIdx.x;
    if (i < N) scores[i] = 1.f / (1.f + __expf(-bn[0]));
}

// ---------------------------------------------------------------------------

extern "C" void kernel_launch(void* const* d_in, const int* in_sizes, int n_in,
                              void* d_out, int out_size, void* d_ws, size_t ws_size,
                              hipStream_t stream) {
    const float* x_host   = (const float*)d_in[0];
    const float* x_vm     = (const float*)d_in[1];
    const float* x_job    = (const float*)d_in[2];
    const float* x_switch = (const float*)d_in[3];
    const int* e_hs_src = (const int*)d_in[4];
    const int* e_hs_dst = (const int*)d_in[5];
    const int* e_vh_src = (const int*)d_in[6];
    const int* e_vh_dst = (const int*)d_in[7];
    const int* e_jv_src = (const int*)d_in[8];
    const int* e_jv_dst = (const int*)d_in[9];
    const float* Wl_hs = (const float*)d_in[10];
    const float* bl_hs = (const float*)d_in[11];
    const float* Wr_hs = (const float*)d_in[12];
    const float* br_hs = (const float*)d_in[13];
    const float* att_hs = (const float*)d_in[14];
    const float* bias_hs = (const float*)d_in[15];
    const float* Wl_vh = (const float*)d_in[16];
    const float* bl_vh = (const float*)d_in[17];
    const float* Wr_vh = (const float*)d_in[18];
    const float* br_vh = (const float*)d_in[19];
    const float* att_vh = (const float*)d_in[20];
    const float* bias_vh = (const float*)d_in[21];
    const float* Wl_jv = (const float*)d_in[22];
    const float* bl_jv = (const float*)d_in[23];
    const float* Wr_jv = (const float*)d_in[24];
    const float* br_jv = (const float*)d_in[25];
    const float* att_jv = (const float*)d_in[26];
    const float* bias_jv = (const float*)d_in[27];
    const float* W_host   = (const float*)d_in[28];
    const float* b_host   = (const float*)d_in[29];
    const float* W_vm     = (const float*)d_in[30];
    const float* b_vm     = (const float*)d_in[31];
    const float* W_job    = (const float*)d_in[32];
    const float* b_job    = (const float*)d_in[33];
    const float* W_switch = (const float*)d_in[34];
    const float* b_switch = (const float*)d_in[35];

    const int NH  = in_sizes[0] / 64;
    const int NV  = in_sizes[1] / 64;
    const int NJ  = in_sizes[2] / 64;
    const int NSW = in_sizes[3] / 64;
    const int EHS = in_sizes[4];
    const int EVH = in_sizes[6];
    const int EJV = in_sizes[8];

    float* out = (float*)d_out;
    float* s_host = out;
    float* s_vm = out + NH;
    float* s_job = out + NH + NV;
    float* s_sw = out + NH + NV + NJ;
    float* a_hs = out + NH + NV + NJ + NSW;
    float* a_vh = a_hs + (size_t)EHS * 4;
    float* a_jv = a_vh + (size_t)EVH * 4;

    float* ws = (float*)d_ws;

    auto run_rel = [&](const float* x_src, int Ns, const float* x_dst, int Nd,
                       const int* esrc, const int* edst, int E,
                       const float* Wl, const float* bl,
                       const float* Wr, const float* br,
                       const float* att, const float* bias,
                       const float* Wn, const float* bn,
                       float* alpha, float* scores) {
        // arena layout (words):
        float* xl = ws;                                   // Ns*128
        float* xr = xl + (size_t)Ns * 128;                // Nd*128
        unsigned* mk = (unsigned*)(xr + (size_t)Nd * 128);// Nd*4   } zeroed
        float* dn = (float*)(mk + (size_t)Nd * 4);        // Nd*4   } together
        int* hist = (int*)(dn + (size_t)Nd * 4);          // Nd     } (9*Nd)
        int* rowptr = hist + Nd;                          // Nd+1
        int* fillpos = rowptr + Nd + 1;                   // Nd
        int* eidx = fillpos + Nd;                         // E
        int* bsum = eidx + E;                             // 512

        const int nb = (Nd + 255) / 256;                  // <= 391 <= 512

        gemm_xw_kernel<<<(Ns + 63) / 64, 256, 0, stream>>>(x_src, Wl, bl, xl, Ns);
        gemm_xw_kernel<<<(Nd + 63) / 64, 256, 0, stream>>>(x_dst, Wr, br, xr, Nd);

        {   // zero mk + dn + hist (contiguous 9*Nd words)
            size_t n = (size_t)Nd * 9;
            int blocks = (int)((n + 255) / 256);
            if (blocks > 2048) blocks = 2048;
            zero_words_kernel<<<blocks, 256, 0, stream>>>((int*)mk, n);
        }

        // CSR build
        {
            int eb = (E + 255) / 256; if (eb > 2048) eb = 2048;
            hist_kernel<<<eb, 256, 0, stream>>>(edst, hist, E);
            scan1_kernel<<<nb, 256, 0, stream>>>(hist, rowptr, bsum, Nd);
            scan2_kernel<<<1, 512, 0, stream>>>(bsum, nb);
            scan3_kernel<<<nb, 256, 0, stream>>>(rowptr, fillpos, bsum, Nd, E);
            fill_kernel<<<eb, 256, 0, stream>>>(edst, fillpos, eidx, E);
        }

        edge_logits_kernel<<<((size_t)E * 16 + 255) / 256, 256, 0, stream>>>(
            xl, xr, esrc, edst, att, alpha, mk, E);
        edge_exp_kernel<<<((size_t)E * 4 + 255) / 256, 256, 0, stream>>>(
            alpha, mk, edst, dn, E * 4);

        aggregate_kernel<<<((size_t)Nd * 64 + 255) / 256, 256, 0, stream>>>(
            alpha, dn, rowptr, eidx, esrc, xl, bias, Wn, bn, scores, Nd);
    };

    // hs: host -> switch
    run_rel(x_host, NH, x_switch, NSW, e_hs_src, e_hs_dst, EHS,
            Wl_hs, bl_hs, Wr_hs, br_hs, att_hs, bias_hs,
            W_switch, b_switch, a_hs, s_sw);
    // vh: vm -> host
    run_rel(x_vm, NV, x_host, NH, e_vh_src, e_vh_dst, EVH,
            Wl_vh, bl_vh, Wr_vh, br_vh, att_vh, bias_vh,
            W_host, b_host, a_vh, s_host);
    // jv: job -> vm
    run_rel(x_job, NJ, x_vm, NV, e_jv_src, e_jv_dst, EJV,
            Wl_jv, bl_jv, Wr_jv, br_jv, att_jv, bias_jv,
            W_vm, b_vm, a_jv, s_vm);

    job_fill_kernel<<<(NJ + 255) / 256, 256, 0, stream>>>(b_job, s_job, NJ);
}

// Round 4
// 817.947 us; speedup vs baseline: 3.7149x; 1.3834x over previous
//
#include <hip/hip_runtime.h>
#include <hip/hip_bf16.h>

// ---------------------------------------------------------------------------
// HeteroIncidentGATv2: 3 bipartite GATv2 relations (H=4, C=32, HC=128)
//   hs: host->switch (200K edges), vh: vm->host (400K), jv: job->vm (800K)
//
// R4 changes vs R3 (1131 us; aggregate latency-bound: HBM 23%, VALU 25%):
//   - FUSED flash-style per-dst kernel: one wave per dst does ONE pass over
//     its edges with online softmax (running m, s, rescaled acc), xr/att in
//     registers, raw logits stored to d_out; readout fused. Replaces
//     edge_logits + edge_exp + aggregate (+ their atomics and zero-fills).
//   - fill_kernel writes packed int2{edge,src} (one 8B load/edge, one fewer
//     dependent indirection); next-edge software prefetch in the hot loop.
//   - alpha_kernel (edge-parallel, coalesced) converts logits -> alpha.
// ---------------------------------------------------------------------------

#define SLOPE_ATT 0.2f
#define SLOPE_OUT 0.01f

// ---------------------------------------------------------------------------
__global__ __launch_bounds__(256) void zero_words_kernel(int* __restrict__ p, size_t n) {
    size_t i = (size_t)blockIdx.x * 256 + threadIdx.x;
    size_t stride = (size_t)gridDim.x * 256;
    for (; i < n; i += stride) p[i] = 0;
}

// ---------------------------------------------------------------------------
// GEMM: Y[M,128] = X[M,64] @ W[64,128] + b[128]
// ---------------------------------------------------------------------------
__global__ __launch_bounds__(256) void gemm_xw_kernel(
    const float* __restrict__ X, const float* __restrict__ W,
    const float* __restrict__ b, float* __restrict__ Y, int M) {
    __shared__ float sW[64 * 128];
    __shared__ float sX[64][68];

    const int tid = threadIdx.x;
    const int block_row = blockIdx.x * 64;

    for (int i = tid; i < 64 * 128 / 4; i += 256)
        ((float4*)sW)[i] = ((const float4*)W)[i];

    for (int i = tid; i < 64 * 16; i += 256) {
        int r = i >> 4, c4 = i & 15;
        int gr = block_row + r;
        float4 v = make_float4(0.f, 0.f, 0.f, 0.f);
        if (gr < M) v = ((const float4*)X)[(size_t)gr * 16 + c4];
        *(float4*)&sX[r][c4 * 4] = v;
    }
    __syncthreads();

    const int tx = tid & 31;
    const int ty = tid >> 5;

    float acc[8][4] = {};
    for (int k = 0; k < 64; k += 4) {
        float4 w0 = *(const float4*)&sW[(k + 0) * 128 + tx * 4];
        float4 w1 = *(const float4*)&sW[(k + 1) * 128 + tx * 4];
        float4 w2 = *(const float4*)&sW[(k + 2) * 128 + tx * 4];
        float4 w3 = *(const float4*)&sW[(k + 3) * 128 + tx * 4];
#pragma unroll
        for (int r = 0; r < 8; r++) {
            float4 xv = *(const float4*)&sX[ty + r * 8][k];
            acc[r][0] += xv.x * w0.x + xv.y * w1.x + xv.z * w2.x + xv.w * w3.x;
            acc[r][1] += xv.x * w0.y + xv.y * w1.y + xv.z * w2.y + xv.w * w3.y;
            acc[r][2] += xv.x * w0.z + xv.y * w1.z + xv.z * w2.z + xv.w * w3.z;
            acc[r][3] += xv.x * w0.w + xv.y * w1.w + xv.z * w2.w + xv.w * w3.w;
        }
    }

    float4 bv = ((const float4*)b)[tx];
#pragma unroll
    for (int r = 0; r < 8; r++) {
        int gr = block_row + ty + r * 8;
        if (gr < M) {
            float4 o = make_float4(acc[r][0] + bv.x, acc[r][1] + bv.y,
                                   acc[r][2] + bv.z, acc[r][3] + bv.w);
            ((float4*)Y)[(size_t)gr * 32 + tx] = o;
        }
    }
}

// ---------------------------------------------------------------------------
// CSR build: histogram -> 3-kernel exclusive scan -> fill (packed {edge,src})
// ---------------------------------------------------------------------------
__global__ __launch_bounds__(256) void hist_kernel(
    const int* __restrict__ dst, int* __restrict__ hist, int E) {
    int i = blockIdx.x * 256 + threadIdx.x;
    int stride = gridDim.x * 256;
    for (; i < E; i += stride) atomicAdd(&hist[dst[i]], 1);
}

__global__ __launch_bounds__(256) void scan1_kernel(
    const int* __restrict__ hist, int* __restrict__ rowptr,
    int* __restrict__ bsum, int n) {
    __shared__ int s[256];
    int tid = threadIdx.x;
    int i = blockIdx.x * 256 + tid;
    int v = (i < n) ? hist[i] : 0;
    s[tid] = v;
    __syncthreads();
    for (int off = 1; off < 256; off <<= 1) {
        int t = (tid >= off) ? s[tid - off] : 0;
        __syncthreads();
        s[tid] += t;
        __syncthreads();
    }
    if (i < n) rowptr[i] = s[tid] - v;
    if (tid == 255) bsum[blockIdx.x] = s[255];
}

__global__ __launch_bounds__(512) void scan2_kernel(int* __restrict__ bsum, int nb) {
    __shared__ int s[512];
    int tid = threadIdx.x;
    int v = (tid < nb) ? bsum[tid] : 0;
    s[tid] = v;
    __syncthreads();
    for (int off = 1; off < 512; off <<= 1) {
        int t = (tid >= off) ? s[tid - off] : 0;
        __syncthreads();
        s[tid] += t;
        __syncthreads();
    }
    if (tid < nb) bsum[tid] = s[tid] - v;
}

__global__ __launch_bounds__(256) void scan3_kernel(
    int* __restrict__ rowptr, int* __restrict__ fillpos,
    const int* __restrict__ bsum, int n, int E) {
    int i = blockIdx.x * 256 + threadIdx.x;
    if (i < n) {
        int v = rowptr[i] + bsum[blockIdx.x];
        rowptr[i] = v;
        fillpos[i] = v;
    }
    if (i == 0) rowptr[n] = E;
}

__global__ __launch_bounds__(256) void fill_kernel(
    const int* __restrict__ dst, const int* __restrict__ src,
    int* __restrict__ fillpos, int2* __restrict__ es, int E) {
    int i = blockIdx.x * 256 + threadIdx.x;
    int stride = gridDim.x * 256;
    for (; i < E; i += stride) {
        int pos = atomicAdd(&fillpos[dst[i]], 1);
        es[pos] = make_int2(i, src[i]);
    }
}

// ---------------------------------------------------------------------------
// Fused GATv2 per-dst kernel (flash-style online softmax), one 64-lane wave
// per dst node, 2 channels/lane (HC=128). Single pass over the edge list:
//   p_eh = sum_c lrelu(xl[s] + xr[d], 0.2) * att        (16-lane reduce)
//   m,s,acc updated online (rescale on new max); logits stored (orig order)
// Epilogue: out = acc/s; scores = sigmoid(lrelu(out+bias,.01).Wn + bn);
// m/denom stored per (dst,head) for the alpha pass.
// ---------------------------------------------------------------------------
__global__ __launch_bounds__(256) void fused_agg_kernel(
    const float* __restrict__ xl, const float* __restrict__ xr,
    const float* __restrict__ att,
    const int* __restrict__ rowptr, const int2* __restrict__ es,
    float* __restrict__ lg_out,   // [E,4] original edge order (d_out alpha slot)
    float* __restrict__ m_out, float* __restrict__ dn_out,   // [Nd,4]
    const float* __restrict__ bias, const float* __restrict__ Wn,
    const float* __restrict__ bn, float* __restrict__ scores, int Nd) {
    int wid = (blockIdx.x * 256 + threadIdx.x) >> 6;
    int l = threadIdx.x & 63;
    if (wid >= Nd) return;
    int h = l >> 4;                       // head owning channels 2l,2l+1

    int beg = rowptr[wid], end = rowptr[wid + 1];
    float2 xrv = ((const float2*)(xr + (size_t)wid * 128))[l];
    float2 av  = ((const float2*)att)[l];

    float m = -INFINITY, ssum = 0.f;
    float2 acc = make_float2(0.f, 0.f);

    // software-pipelined: prefetch next edge's {e,src} and xl row
    int2 en; float2 xn;
    if (beg < end) {
        en = es[beg];
        xn = ((const float2*)(xl + (size_t)en.y * 128))[l];
    }
    for (int j = beg; j < end; j++) {
        int2 ec = en; float2 x = xn;
        int jn = j + 1;
        if (jn < end) {
            en = es[jn];
            xn = ((const float2*)(xl + (size_t)en.y * 128))[l];
        }
        float v0 = x.x + xrv.x; v0 = v0 > 0.f ? v0 : SLOPE_ATT * v0;
        float v1 = x.y + xrv.y; v1 = v1 > 0.f ? v1 : SLOPE_ATT * v1;
        float p = v0 * av.x + v1 * av.y;
        p += __shfl_xor(p, 1);
        p += __shfl_xor(p, 2);
        p += __shfl_xor(p, 4);
        p += __shfl_xor(p, 8);            // logit for head h, all 16 lanes
        if ((l & 15) == 0) lg_out[(size_t)ec.x * 4 + h] = p;
        float mnew = fmaxf(m, p);
        float scale = __expf(m - mnew);   // first iter: exp(-inf)=0
        float w = __expf(p - mnew);
        ssum = ssum * scale + w;
        acc.x = acc.x * scale + w * x.x;
        acc.y = acc.y * scale + w * x.y;
        m = mnew;
    }

    if ((l & 15) == 0) {
        m_out[(size_t)wid * 4 + h] = m;
        dn_out[(size_t)wid * 4 + h] = ssum;
    }

    float r = (end > beg) ? 1.f / ssum : 0.f;
    float2 bb = ((const float2*)bias)[l];
    float2 w2 = ((const float2*)Wn)[l];
    float o0 = acc.x * r + bb.x; o0 = o0 > 0.f ? o0 : SLOPE_OUT * o0;
    float o1 = acc.y * r + bb.y; o1 = o1 > 0.f ? o1 : SLOPE_OUT * o1;
    float pr = o0 * w2.x + o1 * w2.y;
#pragma unroll
    for (int off = 1; off < 64; off <<= 1) pr += __shfl_xor(pr, off);
    if (l == 0) scores[wid] = 1.f / (1.f + __expf(-(pr + bn[0])));
}

// ---------------------------------------------------------------------------
// alpha[e,h] = exp(lg[e,h] - m[dst,h]) / denom[dst,h]   (in place over lg)
// ---------------------------------------------------------------------------
__global__ __launch_bounds__(256) void alpha_kernel(
    float* __restrict__ lg, const int* __restrict__ dst,
    const float* __restrict__ m, const float* __restrict__ dn, int E4) {
    int i = blockIdx.x * 256 + threadIdx.x;
    if (i >= E4) return;
    int e = i >> 2, h = i & 3;
    int d = dst[e];
    lg[i] = __expf(lg[i] - m[(size_t)d * 4 + h]) / dn[(size_t)d * 4 + h];
}

__global__ __launch_bounds__(256) void job_fill_kernel(
    const float* __restrict__ bn, float* __restrict__ scores, int N) {
    int i = blockIdx.x * 256 + threadIdx.x;
    if (i < N) scores[i] = 1.f / (1.f + __expf(-bn[0]));
}

// ---------------------------------------------------------------------------

extern "C" void kernel_launch(void* const* d_in, const int* in_sizes, int n_in,
                              void* d_out, int out_size, void* d_ws, size_t ws_size,
                              hipStream_t stream) {
    const float* x_host   = (const float*)d_in[0];
    const float* x_vm     = (const float*)d_in[1];
    const float* x_job    = (const float*)d_in[2];
    const float* x_switch = (const float*)d_in[3];
    const int* e_hs_src = (const int*)d_in[4];
    const int* e_hs_dst = (const int*)d_in[5];
    const int* e_vh_src = (const int*)d_in[6];
    const int* e_vh_dst = (const int*)d_in[7];
    const int* e_jv_src = (const int*)d_in[8];
    const int* e_jv_dst = (const int*)d_in[9];
    const float* Wl_hs = (const float*)d_in[10];
    const float* bl_hs = (const float*)d_in[11];
    const float* Wr_hs = (const float*)d_in[12];
    const float* br_hs = (const float*)d_in[13];
    const float* att_hs = (const float*)d_in[14];
    const float* bias_hs = (const float*)d_in[15];
    const float* Wl_vh = (const float*)d_in[16];
    const float* bl_vh = (const float*)d_in[17];
    const float* Wr_vh = (const float*)d_in[18];
    const float* br_vh = (const float*)d_in[19];
    const float* att_vh = (const float*)d_in[20];
    const float* bias_vh = (const float*)d_in[21];
    const float* Wl_jv = (const float*)d_in[22];
    const float* bl_jv = (const float*)d_in[23];
    const float* Wr_jv = (const float*)d_in[24];
    const float* br_jv = (const float*)d_in[25];
    const float* att_jv = (const float*)d_in[26];
    const float* bias_jv = (const float*)d_in[27];
    const float* W_host   = (const float*)d_in[28];
    const float* b_host   = (const float*)d_in[29];
    const float* W_vm     = (const float*)d_in[30];
    const float* b_vm     = (const float*)d_in[31];
    const float* W_job    = (const float*)d_in[32];
    const float* b_job    = (const float*)d_in[33];
    const float* W_switch = (const float*)d_in[34];
    const float* b_switch = (const float*)d_in[35];

    const int NH  = in_sizes[0] / 64;
    const int NV  = in_sizes[1] / 64;
    const int NJ  = in_sizes[2] / 64;
    const int NSW = in_sizes[3] / 64;
    const int EHS = in_sizes[4];
    const int EVH = in_sizes[6];
    const int EJV = in_sizes[8];

    float* out = (float*)d_out;
    float* s_host = out;
    float* s_vm = out + NH;
    float* s_job = out + NH + NV;
    float* s_sw = out + NH + NV + NJ;
    float* a_hs = out + NH + NV + NJ + NSW;
    float* a_vh = a_hs + (size_t)EHS * 4;
    float* a_jv = a_vh + (size_t)EVH * 4;

    float* ws = (float*)d_ws;

    auto run_rel = [&](const float* x_src, int Ns, const float* x_dst, int Nd,
                       const int* esrc, const int* edst, int E,
                       const float* Wl, const float* bl,
                       const float* Wr, const float* br,
                       const float* att, const float* bias,
                       const float* Wn, const float* bn,
                       float* alpha, float* scores) {
        // arena layout (32-bit words; keep 8B alignment for es)
        float* xl = ws;                                    // Ns*128
        float* xr = xl + (size_t)Ns * 128;                 // Nd*128
        int* hist = (int*)(xr + (size_t)Nd * 128);         // Nd (zeroed)
        int* rowptr = hist + Nd;                           // Nd+2 (pad)
        int* fillpos = rowptr + Nd + 2;                    // Nd
        float* m = (float*)(fillpos + Nd);                 // Nd*4
        float* dn = m + (size_t)Nd * 4;                    // Nd*4
        int* bsum = (int*)(dn + (size_t)Nd * 4);           // 512
        int2* es = (int2*)(bsum + 512);                    // E int2

        const int nb = (Nd + 255) / 256;                   // <= 391

        gemm_xw_kernel<<<(Ns + 63) / 64, 256, 0, stream>>>(x_src, Wl, bl, xl, Ns);
        gemm_xw_kernel<<<(Nd + 63) / 64, 256, 0, stream>>>(x_dst, Wr, br, xr, Nd);

        {   // zero hist
            int blocks = (Nd + 255) / 256; if (blocks > 1024) blocks = 1024;
            zero_words_kernel<<<blocks, 256, 0, stream>>>(hist, (size_t)Nd);
        }

        {   // CSR
            int eb = (E + 255) / 256; if (eb > 2048) eb = 2048;
            hist_kernel<<<eb, 256, 0, stream>>>(edst, hist, E);
            scan1_kernel<<<nb, 256, 0, stream>>>(hist, rowptr, bsum, Nd);
            scan2_kernel<<<1, 512, 0, stream>>>(bsum, nb);
            scan3_kernel<<<nb, 256, 0, stream>>>(rowptr, fillpos, bsum, Nd, E);
            fill_kernel<<<eb, 256, 0, stream>>>(edst, esrc, fillpos, es, E);
        }

        fused_agg_kernel<<<((size_t)Nd * 64 + 255) / 256, 256, 0, stream>>>(
            xl, xr, att, rowptr, es, alpha, m, dn, bias, Wn, bn, scores, Nd);

        alpha_kernel<<<((size_t)E * 4 + 255) / 256, 256, 0, stream>>>(
            alpha, edst, m, dn, E * 4);
    };

    // hs: host -> switch
    run_rel(x_host, NH, x_switch, NSW, e_hs_src, e_hs_dst, EHS,
            Wl_hs, bl_hs, Wr_hs, br_hs, att_hs, bias_hs,
            W_switch, b_switch, a_hs, s_sw);
    // vh: vm -> host
    run_rel(x_vm, NV, x_host, NH, e_vh_src, e_vh_dst, EVH,
            Wl_vh, bl_vh, Wr_vh, br_vh, att_vh, bias_vh,
            W_host, b_host, a_vh, s_host);
    // jv: job -> vm
    run_rel(x_job, NJ, x_vm, NV, e_jv_src, e_jv_dst, EJV,
            Wl_jv, bl_jv, Wr_jv, br_jv, att_jv, bias_jv,
            W_vm, b_vm, a_jv, s_vm);

    job_fill_kernel<<<(NJ + 255) / 256, 256, 0, stream>>>(b_job, s_job, NJ);
}

// Round 5
// 744.936 us; speedup vs baseline: 4.0790x; 1.0980x over previous
//
#include <hip/hip_runtime.h>
#include <hip/hip_bf16.h>

// ---------------------------------------------------------------------------
// HeteroIncidentGATv2: 3 bipartite GATv2 relations (H=4, C=32, HC=128)
//   hs: host->switch (200K), vh: vm->host (400K), jv: job->vm (800K)
//
// R5 changes vs R4 (818 us; agg=234us, rest mostly small-kernel overhead
// across 31 dispatches):
//   - merged segmented CSR build for all relations (6 launches total)
//   - dual-GEMM per relation; merged alpha pass; 13 dispatches total
//   - fused_agg: single-exp online-softmax update + 2-edge unrolled loop
// ---------------------------------------------------------------------------

#define SLOPE_ATT 0.2f
#define SLOPE_OUT 0.01f

// ---------------------------------------------------------------------------
__global__ __launch_bounds__(256) void zero_words_kernel(int* __restrict__ p, size_t n) {
    size_t i = (size_t)blockIdx.x * 256 + threadIdx.x;
    size_t stride = (size_t)gridDim.x * 256;
    for (; i < n; i += stride) p[i] = 0;
}

// ---------------------------------------------------------------------------
// Dual GEMM: two independent Y[M,128] = X[M,64] @ W[64,128] + b in one grid.
// ---------------------------------------------------------------------------
__global__ __launch_bounds__(256) void gemm2_kernel(
    const float* __restrict__ X1, const float* __restrict__ W1,
    const float* __restrict__ b1, float* __restrict__ Y1, int M1, int nb1,
    const float* __restrict__ X2, const float* __restrict__ W2,
    const float* __restrict__ b2, float* __restrict__ Y2, int M2) {
    __shared__ float sW[64 * 128];
    __shared__ float sX[64][68];

    const float* X; const float* W; const float* b; float* Y; int M, block_row;
    if ((int)blockIdx.x < nb1) {
        X = X1; W = W1; b = b1; Y = Y1; M = M1; block_row = blockIdx.x * 64;
    } else {
        X = X2; W = W2; b = b2; Y = Y2; M = M2; block_row = (blockIdx.x - nb1) * 64;
    }

    const int tid = threadIdx.x;

    for (int i = tid; i < 64 * 128 / 4; i += 256)
        ((float4*)sW)[i] = ((const float4*)W)[i];

    for (int i = tid; i < 64 * 16; i += 256) {
        int r = i >> 4, c4 = i & 15;
        int gr = block_row + r;
        float4 v = make_float4(0.f, 0.f, 0.f, 0.f);
        if (gr < M) v = ((const float4*)X)[(size_t)gr * 16 + c4];
        *(float4*)&sX[r][c4 * 4] = v;
    }
    __syncthreads();

    const int tx = tid & 31;
    const int ty = tid >> 5;

    float acc[8][4] = {};
    for (int k = 0; k < 64; k += 4) {
        float4 w0 = *(const float4*)&sW[(k + 0) * 128 + tx * 4];
        float4 w1 = *(const float4*)&sW[(k + 1) * 128 + tx * 4];
        float4 w2 = *(const float4*)&sW[(k + 2) * 128 + tx * 4];
        float4 w3 = *(const float4*)&sW[(k + 3) * 128 + tx * 4];
#pragma unroll
        for (int r = 0; r < 8; r++) {
            float4 xv = *(const float4*)&sX[ty + r * 8][k];
            acc[r][0] += xv.x * w0.x + xv.y * w1.x + xv.z * w2.x + xv.w * w3.x;
            acc[r][1] += xv.x * w0.y + xv.y * w1.y + xv.z * w2.y + xv.w * w3.y;
            acc[r][2] += xv.x * w0.z + xv.y * w1.z + xv.z * w2.z + xv.w * w3.z;
            acc[r][3] += xv.x * w0.w + xv.y * w1.w + xv.z * w2.w + xv.w * w3.w;
        }
    }

    float4 bv = ((const float4*)b)[tx];
#pragma unroll
    for (int r = 0; r < 8; r++) {
        int gr = block_row + ty + r * 8;
        if (gr < M) {
            float4 o = make_float4(acc[r][0] + bv.x, acc[r][1] + bv.y,
                                   acc[r][2] + bv.z, acc[r][3] + bv.w);
            ((float4*)Y)[(size_t)gr * 32 + tx] = o;
        }
    }
}

// ---------------------------------------------------------------------------
// Merged segmented CSR build. hist/rowptr/fillpos/m/dn use PADDED node bases
// (segment sizes rounded to 256). es arrays are per relation.
// ---------------------------------------------------------------------------
__global__ __launch_bounds__(256) void hist3_kernel(
    const int* __restrict__ d0, const int* __restrict__ d1,
    const int* __restrict__ d2, int* __restrict__ hist,
    int E0, int E1, int E2, int pb1, int pb2) {
    int i = blockIdx.x * 256 + threadIdx.x;
    int Etot = E0 + E1 + E2;
    int stride = gridDim.x * 256;
    for (; i < Etot; i += stride) {
        int slot;
        if (i < E0)            slot = d0[i];
        else if (i < E0 + E1)  slot = pb1 + d1[i - E0];
        else                   slot = pb2 + d2[i - E0 - E1];
        atomicAdd(&hist[slot], 1);
    }
}

// segmented per-256-block exclusive scan; nb0/nb1/nb2 blocks per relation
__global__ __launch_bounds__(256) void scan1_kernel(
    const int* __restrict__ hist, int* __restrict__ rowptr,
    int* __restrict__ bsum, int nb0, int nb1, int nb2,
    int n0, int n1, int n2) {
    __shared__ int s[256];
    int b = blockIdx.x;
    int rel, lb, base, n;
    if (b < nb0)            { rel = 0; lb = b;             base = 0;                 n = n0; }
    else if (b < nb0 + nb1) { rel = 1; lb = b - nb0;       base = nb0 * 256;         n = n1; }
    else                    { rel = 2; lb = b - nb0 - nb1; base = (nb0 + nb1) * 256; n = n2; }
    int tid = threadIdx.x;
    int i = lb * 256 + tid;
    int v = (i < n) ? hist[base + i] : 0;
    s[tid] = v;
    __syncthreads();
    for (int off = 1; off < 256; off <<= 1) {
        int t = (tid >= off) ? s[tid - off] : 0;
        __syncthreads();
        s[tid] += t;
        __syncthreads();
    }
    rowptr[base + i] = s[tid] - v;      // padded slots get full prefix (=E_r at i==n)
    if (tid == 255) bsum[rel * 512 + lb] = s[255];
}

// 3 blocks, one per relation; exclusive scan of that relation's block sums
__global__ __launch_bounds__(512) void scan2_kernel(
    int* __restrict__ bsum, int nb0, int nb1, int nb2) {
    __shared__ int s[512];
    int rel = blockIdx.x;
    int nb = rel == 0 ? nb0 : rel == 1 ? nb1 : nb2;
    int* bs = bsum + rel * 512;
    int tid = threadIdx.x;
    int v = (tid < nb) ? bs[tid] : 0;
    s[tid] = v;
    __syncthreads();
    for (int off = 1; off < 512; off <<= 1) {
        int t = (tid >= off) ? s[tid - off] : 0;
        __syncthreads();
        s[tid] += t;
        __syncthreads();
    }
    if (tid < nb) bs[tid] = s[tid] - v;
}

__global__ __launch_bounds__(256) void scan3_kernel(
    int* __restrict__ rowptr, int* __restrict__ fillpos,
    const int* __restrict__ bsum, int nb0, int nb1) {
    int b = blockIdx.x;
    int rel, lb;
    if (b < nb0)            { rel = 0; lb = b; }
    else if (b < nb0 + nb1) { rel = 1; lb = b - nb0; }
    else                    { rel = 2; lb = b - nb0 - nb1; }
    int i = b * 256 + threadIdx.x;      // global padded index
    int v = rowptr[i] + bsum[rel * 512 + lb];
    rowptr[i] = v;
    fillpos[i] = v;
}

__global__ __launch_bounds__(256) void fill3_kernel(
    const int* __restrict__ d0, const int* __restrict__ s0, int2* __restrict__ es0,
    const int* __restrict__ d1, const int* __restrict__ s1, int2* __restrict__ es1,
    const int* __restrict__ d2, const int* __restrict__ s2, int2* __restrict__ es2,
    int* __restrict__ fillpos, int E0, int E1, int E2, int pb1, int pb2) {
    int i = blockIdx.x * 256 + threadIdx.x;
    int Etot = E0 + E1 + E2;
    int stride = gridDim.x * 256;
    for (; i < Etot; i += stride) {
        int le, slot; const int* sp; int2* es;
        if (i < E0)           { le = i;           slot = d0[le];       sp = s0; es = es0; }
        else if (i < E0 + E1) { le = i - E0;      slot = pb1 + d1[le]; sp = s1; es = es1; }
        else                  { le = i - E0 - E1; slot = pb2 + d2[le]; sp = s2; es = es2; }
        int pos = atomicAdd(&fillpos[slot], 1);   // relation-local position
        es[pos] = make_int2(le, sp[le]);
    }
}

// ---------------------------------------------------------------------------
// Fused GATv2 per-dst kernel (online softmax), one 64-lane wave per dst,
// 2 channels/lane. Single-exp update: of {exp(m-mnew), exp(p-mnew)} one is
// exp(0)=1, so compute e=exp(-|p-m|) and select. 2-edge unrolled loop
// overlaps the two independent 4-step shuffle reductions.
// ---------------------------------------------------------------------------
__global__ __launch_bounds__(256) void fused_agg_kernel(
    const float* __restrict__ xl, const float* __restrict__ xr,
    const float* __restrict__ att,
    const int* __restrict__ rowptr, const int2* __restrict__ es,
    float* __restrict__ lg_out,                      // [E,4] original order
    float* __restrict__ m_out, float* __restrict__ dn_out,   // padded-base [*,4]
    const float* __restrict__ bias, const float* __restrict__ Wn,
    const float* __restrict__ bn, float* __restrict__ scores, int Nd) {
    int wid = (blockIdx.x * 256 + threadIdx.x) >> 6;
    int l = threadIdx.x & 63;
    if (wid >= Nd) return;
    int h = l >> 4;

    int beg = rowptr[wid], end = rowptr[wid + 1];
    float2 xrv = ((const float2*)(xr + (size_t)wid * 128))[l];
    float2 av  = ((const float2*)att)[l];

    float m = -INFINITY, ssum = 0.f;
    float2 acc = make_float2(0.f, 0.f);

    auto logit = [&](float2 x) {
        float v0 = x.x + xrv.x; v0 = v0 > 0.f ? v0 : SLOPE_ATT * v0;
        float v1 = x.y + xrv.y; v1 = v1 > 0.f ? v1 : SLOPE_ATT * v1;
        float p = v0 * av.x + v1 * av.y;
        p += __shfl_xor(p, 1);
        p += __shfl_xor(p, 2);
        p += __shfl_xor(p, 4);
        p += __shfl_xor(p, 8);
        return p;
    };
    auto upd = [&](float p, float2 x, int eix) {
        if ((l & 15) == 0) lg_out[(size_t)eix * 4 + h] = p;
        float diff = p - m;
        float e = __expf(-fabsf(diff));           // first iter: exp(-inf)=0
        bool nm = diff > 0.f;
        float scale = nm ? e : 1.f;
        float w = nm ? 1.f : e;
        m = fmaxf(m, p);
        ssum = ssum * scale + w;
        acc.x = acc.x * scale + w * x.x;
        acc.y = acc.y * scale + w * x.y;
    };

    int j = beg;
    for (; j + 1 < end; j += 2) {
        int2 e0 = es[j];
        int2 e1 = es[j + 1];
        float2 x0 = ((const float2*)(xl + (size_t)e0.y * 128))[l];
        float2 x1 = ((const float2*)(xl + (size_t)e1.y * 128))[l];
        float p0 = logit(x0);
        float p1 = logit(x1);
        upd(p0, x0, e0.x);
        upd(p1, x1, e1.x);
    }
    if (j < end) {
        int2 e0 = es[j];
        float2 x0 = ((const float2*)(xl + (size_t)e0.y * 128))[l];
        upd(logit(x0), x0, e0.x);
    }

    if ((l & 15) == 0) {
        m_out[(size_t)wid * 4 + h] = m;
        dn_out[(size_t)wid * 4 + h] = ssum;
    }

    float r = (end > beg) ? 1.f / ssum : 0.f;
    float2 bb = ((const float2*)bias)[l];
    float2 w2 = ((const float2*)Wn)[l];
    float o0 = acc.x * r + bb.x; o0 = o0 > 0.f ? o0 : SLOPE_OUT * o0;
    float o1 = acc.y * r + bb.y; o1 = o1 > 0.f ? o1 : SLOPE_OUT * o1;
    float pr = o0 * w2.x + o1 * w2.y;
#pragma unroll
    for (int off = 1; off < 64; off <<= 1) pr += __shfl_xor(pr, off);
    if (l == 0) scores[wid] = 1.f / (1.f + __expf(-(pr + bn[0])));
}

// ---------------------------------------------------------------------------
// Merged alpha pass over all relations:
// alpha[e,h] = exp(lg[e,h] - m[d,h]) / dn[d,h], in place over lg (contiguous
// a_hs|a_vh|a_jv in d_out). m/dn indexed by padded node base.
// ---------------------------------------------------------------------------
__global__ __launch_bounds__(256) void alpha3_kernel(
    float* __restrict__ lg,
    const int* __restrict__ d0, const int* __restrict__ d1,
    const int* __restrict__ d2,
    const float* __restrict__ m, const float* __restrict__ dn,
    int E0, int E1, int E2, int pb1, int pb2) {
    int i = blockIdx.x * 256 + threadIdx.x;
    int tot = (E0 + E1 + E2) * 4;
    if (i >= tot) return;
    int e = i >> 2, h = i & 3;
    int d;
    if (e < E0)           d = d0[e];
    else if (e < E0 + E1) d = pb1 + d1[e - E0];
    else                  d = pb2 + d2[e - E0 - E1];
    lg[i] = __expf(lg[i] - m[(size_t)d * 4 + h]) / dn[(size_t)d * 4 + h];
}

__global__ __launch_bounds__(256) void job_fill_kernel(
    const float* __restrict__ bn, float* __restrict__ scores, int N) {
    int i = blockIdx.x * 256 + threadIdx.x;
    if (i < N) scores[i] = 1.f / (1.f + __expf(-bn[0]));
}

// ---------------------------------------------------------------------------

extern "C" void kernel_launch(void* const* d_in, const int* in_sizes, int n_in,
                              void* d_out, int out_size, void* d_ws, size_t ws_size,
                              hipStream_t stream) {
    const float* x_host   = (const float*)d_in[0];
    const float* x_vm     = (const float*)d_in[1];
    const float* x_job    = (const float*)d_in[2];
    const float* x_switch = (const float*)d_in[3];
    const int* e_hs_src = (const int*)d_in[4];
    const int* e_hs_dst = (const int*)d_in[5];
    const int* e_vh_src = (const int*)d_in[6];
    const int* e_vh_dst = (const int*)d_in[7];
    const int* e_jv_src = (const int*)d_in[8];
    const int* e_jv_dst = (const int*)d_in[9];
    const float* Wl_hs = (const float*)d_in[10];
    const float* bl_hs = (const float*)d_in[11];
    const float* Wr_hs = (const float*)d_in[12];
    const float* br_hs = (const float*)d_in[13];
    const float* att_hs = (const float*)d_in[14];
    const float* bias_hs = (const float*)d_in[15];
    const float* Wl_vh = (const float*)d_in[16];
    const float* bl_vh = (const float*)d_in[17];
    const float* Wr_vh = (const float*)d_in[18];
    const float* br_vh = (const float*)d_in[19];
    const float* att_vh = (const float*)d_in[20];
    const float* bias_vh = (const float*)d_in[21];
    const float* Wl_jv = (const float*)d_in[22];
    const float* bl_jv = (const float*)d_in[23];
    const float* Wr_jv = (const float*)d_in[24];
    const float* br_jv = (const float*)d_in[25];
    const float* att_jv = (const float*)d_in[26];
    const float* bias_jv = (const float*)d_in[27];
    const float* W_host   = (const float*)d_in[28];
    const float* b_host   = (const float*)d_in[29];
    const float* W_vm     = (const float*)d_in[30];
    const float* b_vm     = (const float*)d_in[31];
    const float* W_job    = (const float*)d_in[32];
    const float* b_job    = (const float*)d_in[33];
    const float* W_switch = (const float*)d_in[34];
    const float* b_switch = (const float*)d_in[35];

    const int NH  = in_sizes[0] / 64;
    const int NV  = in_sizes[1] / 64;
    const int NJ  = in_sizes[2] / 64;
    const int NSW = in_sizes[3] / 64;
    const int EHS = in_sizes[4];
    const int EVH = in_sizes[6];
    const int EJV = in_sizes[8];

    float* out = (float*)d_out;
    float* s_host = out;
    float* s_vm = out + NH;
    float* s_job = out + NH + NV;
    float* s_sw = out + NH + NV + NJ;
    float* a_hs = out + NH + NV + NJ + NSW;
    float* a_vh = a_hs + (size_t)EHS * 4;
    float* a_jv = a_vh + (size_t)EVH * 4;

    // padded segment geometry (dst order: hs=switch, vh=host, jv=vm)
    const int nb0 = (NSW + 255) / 256, nb1 = (NH + 255) / 256, nb2 = (NV + 255) / 256;
    const int pb1 = nb0 * 256, pb2 = (nb0 + nb1) * 256;
    const int ptot = (nb0 + nb1 + nb2) * 256;

    // -------- persistent region --------
    float* ws = (float*)d_ws;
    int2* es_hs = (int2*)ws;                   // EHS
    int2* es_vh = es_hs + EHS;                 // EVH
    int2* es_jv = es_vh + EVH;                 // EJV
    int* hist   = (int*)(es_jv + EJV);         // ptot (zeroed)
    int* rowptr = hist + ptot;                 // ptot
    int* fillpos= rowptr + ptot;               // ptot
    float* m_all  = (float*)(fillpos + ptot);  // ptot*4
    float* dn_all = m_all + (size_t)ptot * 4;  // ptot*4
    int* bsum   = (int*)(dn_all + (size_t)ptot * 4);   // 3*512
    float* arena = (float*)(bsum + 3 * 512);   // per-relation xl|xr

    // -------- CSR build (all relations) --------
    {
        int blocks = (ptot + 255) / 256;
        zero_words_kernel<<<blocks, 256, 0, stream>>>(hist, (size_t)ptot);
        int Etot = EHS + EVH + EJV;
        int eb = (Etot + 255) / 256; if (eb > 4096) eb = 4096;
        hist3_kernel<<<eb, 256, 0, stream>>>(e_hs_dst, e_vh_dst, e_jv_dst,
                                             hist, EHS, EVH, EJV, pb1, pb2);
        scan1_kernel<<<nb0 + nb1 + nb2, 256, 0, stream>>>(
            hist, rowptr, bsum, nb0, nb1, nb2, NSW, NH, NV);
        scan2_kernel<<<3, 512, 0, stream>>>(bsum, nb0, nb1, nb2);
        scan3_kernel<<<nb0 + nb1 + nb2, 256, 0, stream>>>(rowptr, fillpos, bsum, nb0, nb1);
        fill3_kernel<<<eb, 256, 0, stream>>>(
            e_hs_dst, e_hs_src, es_hs, e_vh_dst, e_vh_src, es_vh,
            e_jv_dst, e_jv_src, es_jv, fillpos, EHS, EVH, EJV, pb1, pb2);
    }

    // -------- per relation: dual GEMM + fused aggregate --------
    auto run_rel = [&](const float* x_src, int Ns, const float* x_dst, int Nd,
                       int pbase, const int2* es, int E,
                       const float* Wl, const float* bl,
                       const float* Wr, const float* br,
                       const float* att, const float* bias,
                       const float* Wn, const float* bn,
                       float* alpha, float* scores) {
        float* xl = arena;
        float* xr = xl + (size_t)Ns * 128;
        int gb1 = (Ns + 63) / 64, gb2 = (Nd + 63) / 64;
        gemm2_kernel<<<gb1 + gb2, 256, 0, stream>>>(
            x_src, Wl, bl, xl, Ns, gb1, x_dst, Wr, br, xr, Nd);
        fused_agg_kernel<<<((size_t)Nd * 64 + 255) / 256, 256, 0, stream>>>(
            xl, xr, att, rowptr + pbase, es, alpha,
            m_all + (size_t)pbase * 4, dn_all + (size_t)pbase * 4,
            bias, Wn, bn, scores, Nd);
    };

    run_rel(x_host, NH, x_switch, NSW, 0,   es_hs, EHS,
            Wl_hs, bl_hs, Wr_hs, br_hs, att_hs, bias_hs,
            W_switch, b_switch, a_hs, s_sw);
    run_rel(x_vm, NV, x_host, NH, pb1, es_vh, EVH,
            Wl_vh, bl_vh, Wr_vh, br_vh, att_vh, bias_vh,
            W_host, b_host, a_vh, s_host);
    run_rel(x_job, NJ, x_vm, NV, pb2, es_jv, EJV,
            Wl_jv, bl_jv, Wr_jv, br_jv, att_jv, bias_jv,
            W_vm, b_vm, a_jv, s_vm);

    // -------- merged alpha + job scores --------
    {
        int tot = (EHS + EVH + EJV) * 4;
        alpha3_kernel<<<(tot + 255) / 256, 256, 0, stream>>>(
            a_hs, e_hs_dst, e_vh_dst, e_jv_dst, m_all, dn_all,
            EHS, EVH, EJV, pb1, pb2);
    }
    job_fill_kernel<<<(NJ + 255) / 256, 256, 0, stream>>>(b_job, s_job, NJ);
}

// Round 6
// 646.415 us; speedup vs baseline: 4.7007x; 1.1524x over previous
//
#include <hip/hip_runtime.h>
#include <hip/hip_bf16.h>

// ---------------------------------------------------------------------------
// HeteroIncidentGATv2: 3 bipartite GATv2 relations (H=4, C=32, HC=128)
//   hs: host->switch (200K), vh: vm->host (400K), jv: job->vm (800K)
//
// R6 changes vs R5 (745 us; fill3=131us top, whole CSR build ~200us of
// latency-bound atomics + scatter with 8x write amplification):
//   - CSR build REPLACED by per-dst atomic linked list: one atomicExch per
//     edge + coalesced int2{next,src} store. No hist/scan/fill.
//   - link pass interleaved with the hs GEMM pair in one launch (r-stride
//     block mapping): compute-bound GEMM co-schedules with latency-bound
//     atomics.
//   - agg walks the list (2-deep chain: nxt[e] -> xl row, same depth as R5).
//   - alpha + job_fill merged. 8 launches total (was 13).
// ---------------------------------------------------------------------------

#define SLOPE_ATT 0.2f
#define SLOPE_OUT 0.01f

// ---------------------------------------------------------------------------
__global__ __launch_bounds__(256) void init_kernel(int* __restrict__ p, size_t n, int val) {
    size_t i = (size_t)blockIdx.x * 256 + threadIdx.x;
    size_t stride = (size_t)gridDim.x * 256;
    for (; i < n; i += stride) p[i] = val;
}

// ---------------------------------------------------------------------------
// GEMM tile body: Y[64,128] tile = X[64,64] @ W[64,128] + b
// ---------------------------------------------------------------------------
__device__ __forceinline__ void gemm_tile(
    const float* __restrict__ X, const float* __restrict__ W,
    const float* __restrict__ bb, float* __restrict__ Y, int M, int block_row,
    float* sW, float (*sX)[68]) {
    const int tid = threadIdx.x;

    for (int i = tid; i < 64 * 128 / 4; i += 256)
        ((float4*)sW)[i] = ((const float4*)W)[i];

    for (int i = tid; i < 64 * 16; i += 256) {
        int r = i >> 4, c4 = i & 15;
        int gr = block_row + r;
        float4 v = make_float4(0.f, 0.f, 0.f, 0.f);
        if (gr < M) v = ((const float4*)X)[(size_t)gr * 16 + c4];
        *(float4*)&sX[r][c4 * 4] = v;
    }
    __syncthreads();

    const int tx = tid & 31;
    const int ty = tid >> 5;

    float acc[8][4] = {};
    for (int k = 0; k < 64; k += 4) {
        float4 w0 = *(const float4*)&sW[(k + 0) * 128 + tx * 4];
        float4 w1 = *(const float4*)&sW[(k + 1) * 128 + tx * 4];
        float4 w2 = *(const float4*)&sW[(k + 2) * 128 + tx * 4];
        float4 w3 = *(const float4*)&sW[(k + 3) * 128 + tx * 4];
#pragma unroll
        for (int r = 0; r < 8; r++) {
            float4 xv = *(const float4*)&sX[ty + r * 8][k];
            acc[r][0] += xv.x * w0.x + xv.y * w1.x + xv.z * w2.x + xv.w * w3.x;
            acc[r][1] += xv.x * w0.y + xv.y * w1.y + xv.z * w2.y + xv.w * w3.y;
            acc[r][2] += xv.x * w0.z + xv.y * w1.z + xv.z * w2.z + xv.w * w3.z;
            acc[r][3] += xv.x * w0.w + xv.y * w1.w + xv.z * w2.w + xv.w * w3.w;
        }
    }

    float4 bv = ((const float4*)bb)[tx];
#pragma unroll
    for (int r = 0; r < 8; r++) {
        int gr = block_row + ty + r * 8;
        if (gr < M) {
            float4 o = make_float4(acc[r][0] + bv.x, acc[r][1] + bv.y,
                                   acc[r][2] + bv.z, acc[r][3] + bv.w);
            ((float4*)Y)[(size_t)gr * 32 + tx] = o;
        }
    }
}

// ---------------------------------------------------------------------------
// Dual GEMM (two independent [M,64]@[64,128]+b jobs in one grid)
// ---------------------------------------------------------------------------
__global__ __launch_bounds__(256) void gemm2_kernel(
    const float* __restrict__ X1, const float* __restrict__ W1,
    const float* __restrict__ b1, float* __restrict__ Y1, int M1, int nb1,
    const float* __restrict__ X2, const float* __restrict__ W2,
    const float* __restrict__ b2, float* __restrict__ Y2, int M2) {
    __shared__ float sW[64 * 128];
    __shared__ float sX[64][68];
    int b = blockIdx.x;
    if (b < nb1) gemm_tile(X1, W1, b1, Y1, M1, b * 64, sW, sX);
    else         gemm_tile(X2, W2, b2, Y2, M2, (b - nb1) * 64, sW, sX);
}

// ---------------------------------------------------------------------------
// Linked-list build (all 3 relations) for each edge e of relation rel:
//   old = atomicExch(&head[pb_rel + dst[e]], e);  nxt[eb_rel + e] = {old, src[e]}
// ---------------------------------------------------------------------------
__device__ __forceinline__ void link_work(
    int linkId, int linkBlocks,
    const int* __restrict__ d0, const int* __restrict__ s0,
    const int* __restrict__ d1, const int* __restrict__ s1,
    const int* __restrict__ d2, const int* __restrict__ s2,
    int* __restrict__ head, int2* __restrict__ nxt,
    int E0, int E1, int E2, int pb1, int pb2) {
    int i = linkId * 256 + threadIdx.x;
    int Etot = E0 + E1 + E2;
    int stride = linkBlocks * 256;
    for (; i < Etot; i += stride) {
        int le, slot; const int* sp;
        if (i < E0)           { le = i;           slot = d0[le];       sp = s0; }
        else if (i < E0 + E1) { le = i - E0;      slot = pb1 + d1[le]; sp = s1; }
        else                  { le = i - E0 - E1; slot = pb2 + d2[le]; sp = s2; }
        int old = atomicExch(&head[slot], le);
        nxt[i] = make_int2(old, sp[le]);     // nxt indexed by GLOBAL edge id
    }
}

// ---------------------------------------------------------------------------
// Mega: link3 interleaved with one dual-GEMM (hs). Gemm blocks are the
// sparse job placed at multiples of r so both kinds are co-resident.
// ---------------------------------------------------------------------------
__global__ __launch_bounds__(256) void mega_link_gemm_kernel(
    // link args
    const int* __restrict__ d0, const int* __restrict__ s0,
    const int* __restrict__ d1, const int* __restrict__ s1,
    const int* __restrict__ d2, const int* __restrict__ s2,
    int* __restrict__ head, int2* __restrict__ nxt,
    int E0, int E1, int E2, int pb1, int pb2,
    // gemm args (dual)
    const float* __restrict__ X1, const float* __restrict__ W1,
    const float* __restrict__ b1, float* __restrict__ Y1, int M1, int nbG1,
    const float* __restrict__ X2, const float* __restrict__ W2,
    const float* __restrict__ b2, float* __restrict__ Y2, int M2,
    int G, int r) {
    __shared__ float sW[64 * 128];
    __shared__ float sX[64][68];
    int b = blockIdx.x;
    int q = b / r, rem = b - q * r;
    if (rem == 0 && q < G) {
        if (q < nbG1) gemm_tile(X1, W1, b1, Y1, M1, q * 64, sW, sX);
        else          gemm_tile(X2, W2, b2, Y2, M2, (q - nbG1) * 64, sW, sX);
    } else {
        int nhb = q + (rem ? 1 : 0); if (nhb > G) nhb = G;
        int linkId = b - nhb;
        link_work(linkId, (int)gridDim.x - G, d0, s0, d1, s1, d2, s2,
                  head, nxt, E0, E1, E2, pb1, pb2);
    }
}

// ---------------------------------------------------------------------------
// Fused GATv2 aggregate per dst (online softmax), one 64-lane wave per dst,
// 2 channels/lane, walking the per-dst linked list.
// ---------------------------------------------------------------------------
__global__ __launch_bounds__(256) void agg_kernel(
    const float* __restrict__ xl, const float* __restrict__ xr,
    const float* __restrict__ att,
    const int* __restrict__ head,      // pre-offset: head_all + pbase
    const int2* __restrict__ nxt,      // pre-offset: nxt_all + ebase
    float* __restrict__ lg_out,        // [E,4] original edge order
    float* __restrict__ m_out, float* __restrict__ dn_out,  // pre-offset
    const float* __restrict__ bias, const float* __restrict__ Wn,
    const float* __restrict__ bn, float* __restrict__ scores, int Nd) {
    int wid = (blockIdx.x * 256 + threadIdx.x) >> 6;
    int l = threadIdx.x & 63;
    if (wid >= Nd) return;
    int h = l >> 4;

    float2 xrv = ((const float2*)(xr + (size_t)wid * 128))[l];
    float2 av  = ((const float2*)att)[l];

    float m = -INFINITY, ssum = 0.f;
    float2 acc = make_float2(0.f, 0.f);

    int e = head[wid];
    bool any = (e >= 0);
    while (e >= 0) {
        int2 ns = nxt[e];                 // {next_edge, src}
        float2 x = ((const float2*)(xl + (size_t)ns.y * 128))[l];
        float v0 = x.x + xrv.x; v0 = v0 > 0.f ? v0 : SLOPE_ATT * v0;
        float v1 = x.y + xrv.y; v1 = v1 > 0.f ? v1 : SLOPE_ATT * v1;
        float p = v0 * av.x + v1 * av.y;
        p += __shfl_xor(p, 1);
        p += __shfl_xor(p, 2);
        p += __shfl_xor(p, 4);
        p += __shfl_xor(p, 8);            // per-head logit (16 lanes)
        if ((l & 15) == 0) lg_out[(size_t)e * 4 + h] = p;
        float diff = p - m;
        float ex = __expf(-fabsf(diff));  // first iter: exp(-inf)=0
        bool nm = diff > 0.f;
        float scale = nm ? ex : 1.f;
        float w = nm ? 1.f : ex;
        m = fmaxf(m, p);
        ssum = ssum * scale + w;
        acc.x = acc.x * scale + w * x.x;
        acc.y = acc.y * scale + w * x.y;
        e = ns.x;
    }

    if ((l & 15) == 0) {
        m_out[(size_t)wid * 4 + h] = m;
        dn_out[(size_t)wid * 4 + h] = ssum;
    }

    float rr = any ? 1.f / ssum : 0.f;
    float2 bb = ((const float2*)bias)[l];
    float2 w2 = ((const float2*)Wn)[l];
    float o0 = acc.x * rr + bb.x; o0 = o0 > 0.f ? o0 : SLOPE_OUT * o0;
    float o1 = acc.y * rr + bb.y; o1 = o1 > 0.f ? o1 : SLOPE_OUT * o1;
    float pr = o0 * w2.x + o1 * w2.y;
#pragma unroll
    for (int off = 1; off < 64; off <<= 1) pr += __shfl_xor(pr, off);
    if (l == 0) scores[wid] = 1.f / (1.f + __expf(-(pr + bn[0])));
}

// ---------------------------------------------------------------------------
// Merged: alpha for all relations + job scores.
// alpha[e,h] = exp(lg[e,h] - m[d,h]) / dn[d,h] in place over lg.
// ---------------------------------------------------------------------------
__global__ __launch_bounds__(256) void alpha_job_kernel(
    float* __restrict__ lg,
    const int* __restrict__ d0, const int* __restrict__ d1,
    const int* __restrict__ d2,
    const float* __restrict__ m, const float* __restrict__ dn,
    int E0, int E1, int E2, int pb1, int pb2, int ab,
    const float* __restrict__ bjob, float* __restrict__ sjob, int NJ) {
    int b = blockIdx.x;
    if (b < ab) {
        int i = b * 256 + threadIdx.x;
        int tot = (E0 + E1 + E2) * 4;
        if (i >= tot) return;
        int e = i >> 2, h = i & 3;
        int d;
        if (e < E0)           d = d0[e];
        else if (e < E0 + E1) d = pb1 + d1[e - E0];
        else                  d = pb2 + d2[e - E0 - E1];
        lg[i] = __expf(lg[i] - m[(size_t)d * 4 + h]) / dn[(size_t)d * 4 + h];
    } else {
        int i = (b - ab) * 256 + threadIdx.x;
        if (i < NJ) sjob[i] = 1.f / (1.f + __expf(-bjob[0]));
    }
}

// ---------------------------------------------------------------------------

extern "C" void kernel_launch(void* const* d_in, const int* in_sizes, int n_in,
                              void* d_out, int out_size, void* d_ws, size_t ws_size,
                              hipStream_t stream) {
    const float* x_host   = (const float*)d_in[0];
    const float* x_vm     = (const float*)d_in[1];
    const float* x_job    = (const float*)d_in[2];
    const float* x_switch = (const float*)d_in[3];
    const int* e_hs_src = (const int*)d_in[4];
    const int* e_hs_dst = (const int*)d_in[5];
    const int* e_vh_src = (const int*)d_in[6];
    const int* e_vh_dst = (const int*)d_in[7];
    const int* e_jv_src = (const int*)d_in[8];
    const int* e_jv_dst = (const int*)d_in[9];
    const float* Wl_hs = (const float*)d_in[10];
    const float* bl_hs = (const float*)d_in[11];
    const float* Wr_hs = (const float*)d_in[12];
    const float* br_hs = (const float*)d_in[13];
    const float* att_hs = (const float*)d_in[14];
    const float* bias_hs = (const float*)d_in[15];
    const float* Wl_vh = (const float*)d_in[16];
    const float* bl_vh = (const float*)d_in[17];
    const float* Wr_vh = (const float*)d_in[18];
    const float* br_vh = (const float*)d_in[19];
    const float* att_vh = (const float*)d_in[20];
    const float* bias_vh = (const float*)d_in[21];
    const float* Wl_jv = (const float*)d_in[22];
    const float* bl_jv = (const float*)d_in[23];
    const float* Wr_jv = (const float*)d_in[24];
    const float* br_jv = (const float*)d_in[25];
    const float* att_jv = (const float*)d_in[26];
    const float* bias_jv = (const float*)d_in[27];
    const float* W_host   = (const float*)d_in[28];
    const float* b_host   = (const float*)d_in[29];
    const float* W_vm     = (const float*)d_in[30];
    const float* b_vm     = (const float*)d_in[31];
    const float* W_job    = (const float*)d_in[32];
    const float* b_job    = (const float*)d_in[33];
    const float* W_switch = (const float*)d_in[34];
    const float* b_switch = (const float*)d_in[35];

    const int NH  = in_sizes[0] / 64;
    const int NV  = in_sizes[1] / 64;
    const int NJ  = in_sizes[2] / 64;
    const int NSW = in_sizes[3] / 64;
    const int EHS = in_sizes[4];
    const int EVH = in_sizes[6];
    const int EJV = in_sizes[8];

    float* out = (float*)d_out;
    float* s_host = out;
    float* s_vm = out + NH;
    float* s_job = out + NH + NV;
    float* s_sw = out + NH + NV + NJ;
    float* a_hs = out + NH + NV + NJ + NSW;
    float* a_vh = a_hs + (size_t)EHS * 4;
    float* a_jv = a_vh + (size_t)EVH * 4;

    // padded dst-segment geometry (order: hs=switch, vh=host, jv=vm)
    const int pb1 = ((NSW + 255) / 256) * 256;
    const int pb2 = pb1 + ((NH + 255) / 256) * 256;
    const int ptot = pb2 + ((NV + 255) / 256) * 256;

    // -------- ws layout --------
    float* ws = (float*)d_ws;
    int2* nxt_all = (int2*)ws;                         // Etot int2 (8B aligned)
    int* head_all = (int*)(nxt_all + (EHS + EVH + EJV));   // ptot
    float* m_all  = (float*)(head_all + ptot);         // ptot*4
    float* dn_all = m_all + (size_t)ptot * 4;          // ptot*4
    float* arena  = dn_all + (size_t)ptot * 4;         // per-relation xl|xr

    // 1) head = -1
    {
        int blocks = (ptot + 255) / 256;
        init_kernel<<<blocks, 256, 0, stream>>>(head_all, (size_t)ptot, -1);
    }

    // 2) mega: link3 (dense) + hs dual-GEMM (sparse, every r-th block)
    float* xl_hs = arena;
    float* xr_hs = xl_hs + (size_t)NH * 128;
    {
        int nbG1 = (NH + 63) / 64;
        int G = nbG1 + (NSW + 63) / 64;
        int linkBlocks = 3072;
        int T = G + linkBlocks;
        int r = T / G; if (r < 1) r = 1;
        // gemm ids live at multiples of r: (G-1)*r <= (G-1)*T/G < T  (ok)
        mega_link_gemm_kernel<<<T, 256, 0, stream>>>(
            e_hs_dst, e_hs_src, e_vh_dst, e_vh_src, e_jv_dst, e_jv_src,
            head_all, nxt_all, EHS, EVH, EJV, pb1, pb2,
            x_host, Wl_hs, bl_hs, xl_hs, NH, nbG1,
            x_switch, Wr_hs, br_hs, xr_hs, NSW, G, r);
    }

    // 3) agg hs (dst = switch)
    agg_kernel<<<((size_t)NSW * 64 + 255) / 256, 256, 0, stream>>>(
        xl_hs, xr_hs, att_hs, head_all + 0, nxt_all + 0,
        a_hs, m_all + 0, dn_all + 0,
        bias_hs, W_switch, b_switch, s_sw, NSW);

    // 4-5) vh relation (dst = host)
    float* xl_vh = arena;
    float* xr_vh = xl_vh + (size_t)NV * 128;
    {
        int nb1 = (NV + 63) / 64;
        gemm2_kernel<<<nb1 + (NH + 63) / 64, 256, 0, stream>>>(
            x_vm, Wl_vh, bl_vh, xl_vh, NV, nb1,
            x_host, Wr_vh, br_vh, xr_vh, NH);
        agg_kernel<<<((size_t)NH * 64 + 255) / 256, 256, 0, stream>>>(
            xl_vh, xr_vh, att_vh, head_all + pb1, nxt_all + EHS,
            a_vh, m_all + (size_t)pb1 * 4, dn_all + (size_t)pb1 * 4,
            bias_vh, W_host, b_host, s_host, NH);
    }

    // 6-7) jv relation (dst = vm)
    float* xl_jv = arena;
    float* xr_jv = xl_jv + (size_t)NJ * 128;
    {
        int nb1 = (NJ + 63) / 64;
        gemm2_kernel<<<nb1 + (NV + 63) / 64, 256, 0, stream>>>(
            x_job, Wl_jv, bl_jv, xl_jv, NJ, nb1,
            x_vm, Wr_jv, br_jv, xr_jv, NV);
        agg_kernel<<<((size_t)NV * 64 + 255) / 256, 256, 0, stream>>>(
            xl_jv, xr_jv, att_jv, head_all + pb2, nxt_all + (EHS + EVH),
            a_jv, m_all + (size_t)pb2 * 4, dn_all + (size_t)pb2 * 4,
            bias_jv, W_vm, b_vm, s_vm, NV);
    }

    // 8) alpha (all relations) + job scores, one launch
    {
        int ab = ((EHS + EVH + EJV) * 4 + 255) / 256;
        int jb = (NJ + 255) / 256;
        alpha_job_kernel<<<ab + jb, 256, 0, stream>>>(
            a_hs, e_hs_dst, e_vh_dst, e_jv_dst, m_all, dn_all,
            EHS, EVH, EJV, pb1, pb2, ab, b_job, s_job, NJ);
    }
}